// Round 3
// baseline (8544.402 us; speedup 1.0000x reference)
//
#include <hip/hip_runtime.h>
#include <math.h>
#include <stdint.h>

typedef unsigned short u16;

__device__ __forceinline__ float b2f(u16 u){
  union{unsigned int i; float f;} v; v.i = ((unsigned int)u)<<16; return v.f;
}
__device__ __forceinline__ u16 f2b(float f){
  union{unsigned int i; float f;} v; v.f = f;
  unsigned int r = (v.i + 0x7FFFu + ((v.i>>16)&1u))>>16;
  return (u16)r;
}
// dual-dtype external loads: isb=1 -> bf16(u16), isb=0 -> float32
__device__ __forceinline__ float ldx(const void* p, size_t i, int isb){
  return isb ? b2f(((const u16*)p)[i]) : ((const float*)p)[i];
}
__device__ __forceinline__ void ld4(const void* p, size_t i, int isb, float* o){
  if (isb){
    ushort4 v = *reinterpret_cast<const ushort4*>((const u16*)p + i);
    o[0]=b2f(v.x); o[1]=b2f(v.y); o[2]=b2f(v.z); o[3]=b2f(v.w);
  } else {
    float4 v = *reinterpret_cast<const float4*>((const float*)p + i);
    o[0]=v.x; o[1]=v.y; o[2]=v.z; o[3]=v.w;
  }
}

// dtype sniffer: bf16 N(0,1) data has exponent field in [110,139] for ~all
// even-indexed u16s; f32 low-mantissa halves are uniform (~12% in window).
__global__ void k_sniff(const void* __restrict__ X, int* __restrict__ flag)
{
  __shared__ int cnt;
  if (threadIdx.x==0) cnt = 0;
  __syncthreads();
  int c = 0;
  for (int t = threadIdx.x; t < 512; t += 256){
    unsigned int u = ((const u16*)X)[2*t];
    int e = (u >> 7) & 0xFF;
    if (e >= 110 && e <= 139) c++;
  }
  atomicAdd(&cnt, c);
  __syncthreads();
  if (threadIdx.x==0) *flag = (cnt > 300) ? 1 : 0;
}

__global__ __launch_bounds__(256) void k_zero(float* __restrict__ p, int n)
{
  int i = blockIdx.x*256 + threadIdx.x;
  if (i < n) p[i] = 0.f;
}

// normalize X, decompose into 10 independent components (bf16)
__global__ __launch_bounds__(256) void k_decompose(
    const void* __restrict__ X, u16* __restrict__ Di, u16* __restrict__ Da,
    u16* __restrict__ Ds, int NH, const int* __restrict__ dflag)
{
  int tid = blockIdx.x*256 + threadIdx.x;
  if (tid >= NH) return;
  int isb = *dflag;
  int n = tid >> 7, k = tid & 127;
  float x[9]; float nrm = 0.f;
#pragma unroll
  for (int i=0;i<9;i++){ x[i]=ldx(X,(size_t)tid*9+i,isb); nrm += x[i]*x[i]; }
  float inv = 1.0f/(nrm+1.0f);
#pragma unroll
  for (int i=0;i<9;i++) x[i]*=inv;
  float i0 = (x[0]+x[4]+x[8])*(1.0f/3.0f);
  Di[tid] = f2b(i0);
  size_t ab = ((size_t)n*3)*128 + k;
  Da[ab      ] = f2b(0.5f*(x[1]-x[3]));
  Da[ab + 128] = f2b(0.5f*(x[2]-x[6]));
  Da[ab + 256] = f2b(0.5f*(x[5]-x[7]));
  size_t sb = ((size_t)n*6)*128 + k;
  Ds[sb      ] = f2b(x[0]-i0);
  Ds[sb + 128] = f2b(0.5f*(x[1]+x[3]));
  Ds[sb + 256] = f2b(0.5f*(x[2]+x[6]));
  Ds[sb + 384] = f2b(x[4]-i0);
  Ds[sb + 512] = f2b(0.5f*(x[5]+x[7]));
  Ds[sb + 640] = f2b(x[8]-i0);
}

// Generic GEMM: C[M,Ncol](bf16) = A[aoff + M,K] * B[boff + Ncol,K]^T
// aoff/boff are ELEMENT offsets applied inside (dtype-correct).
// flags bit0 = silu, bit1 = per-row scale. aext/bext: external operand.
#define BKK 16
__global__ __launch_bounds__(256) void k_gemm(
    const void* __restrict__ A, size_t aoff, const void* __restrict__ Bw, size_t boff,
    const void* __restrict__ bias, const float* __restrict__ rowscale,
    u16* __restrict__ C, int M, int Ncol, int K, int flags,
    int aext, int bext, const int* __restrict__ dflag)
{
  __shared__ __align__(16) float As[BKK][68];
  __shared__ __align__(16) float Bs[BKK][68];
  int isb = *dflag;
  int isbA = aext ? isb : 1;
  int isbB = bext ? isb : 1;
  int tid = threadIdx.x;
  int tx = tid & 15, ty = tid >> 4;
  int n0 = blockIdx.x * 64, m0 = blockIdx.y * 64;
  int arow = tid >> 2, acol = (tid & 3) * 4;
  float acc[4][4];
#pragma unroll
  for (int i=0;i<4;i++)
#pragma unroll
    for (int j=0;j<4;j++) acc[i][j]=0.f;

  for (int k0 = 0; k0 < K; k0 += BKK){
    int gm = m0 + arow;
    float af[4] = {0.f,0.f,0.f,0.f};
    float bf_[4];
    if (gm < M) ld4(A, aoff + (size_t)gm*K + k0 + acol, isbA, af);
    ld4(Bw, boff + (size_t)(n0+arow)*K + k0 + acol, isbB, bf_);
    __syncthreads();
    As[acol+0][arow]=af[0]; As[acol+1][arow]=af[1];
    As[acol+2][arow]=af[2]; As[acol+3][arow]=af[3];
    Bs[acol+0][arow]=bf_[0]; Bs[acol+1][arow]=bf_[1];
    Bs[acol+2][arow]=bf_[2]; Bs[acol+3][arow]=bf_[3];
    __syncthreads();
#pragma unroll
    for (int k=0;k<BKK;k++){
      float4 a4 = *reinterpret_cast<const float4*>(&As[k][ty*4]);
      float4 b4 = *reinterpret_cast<const float4*>(&Bs[k][tx*4]);
      float a[4] = {a4.x,a4.y,a4.z,a4.w};
      float b[4] = {b4.x,b4.y,b4.z,b4.w};
#pragma unroll
      for (int i=0;i<4;i++)
#pragma unroll
        for (int j=0;j<4;j++) acc[i][j] += a[i]*b[j];
    }
  }

#pragma unroll
  for (int i=0;i<4;i++){
    int row = m0 + ty*4 + i;
    if (row >= M) break;
    float rs = (flags & 2) ? rowscale[row] : 1.0f;
    float v[4];
#pragma unroll
    for (int j=0;j<4;j++){
      float t = acc[i][j];
      int col = n0 + tx*4 + j;
      if (bias) t += ldx(bias, col, isbB);
      if (flags & 1) t = t / (1.0f + expf(-t));
      v[j] = t * rs;
    }
    ushort4 pk;
    pk.x=f2b(v[0]); pk.y=f2b(v[1]); pk.z=f2b(v[2]); pk.w=f2b(v[3]);
    *reinterpret_cast<ushort4*>(C + (size_t)row*Ncol + n0 + tx*4) = pk;
  }
}

__global__ __launch_bounds__(256) void k_cutoff(
    const void* __restrict__ ew, int eoff, float* __restrict__ Cc, int ec,
    const int* __restrict__ dflag)
{
  int e = blockIdx.x*256 + threadIdx.x;
  if (e >= ec) return;
  float w = ldx(ew, (size_t)eoff + e, *dflag);
  float c = 0.0f;
  if (w < 4.5f) c = 0.5f*(cosf(w*0.6981317007977318f) + 1.0f);
  Cc[e] = c;
}

// Message passing (chunk [e0,e0+ec)): thread per (edge,channel), 9 atomics.
__global__ __launch_bounds__(256) void k_message(
    const int* __restrict__ ei, int e0, int E, const u16* __restrict__ ea,
    const u16* __restrict__ Pi, const u16* __restrict__ Pa,
    const u16* __restrict__ Ps, const void* __restrict__ b1,
    float* __restrict__ msg, int ec, const int* __restrict__ dflag)
{
  int idx = blockIdx.x*256 + threadIdx.x;
  int e = idx >> 7, c = idx & 127;
  if (e >= ec) return;
  int isb = *dflag;
  int ge = e0 + e;
  int dst = ei[ge], src = ei[E + ge];
  const u16* eap = ea + (size_t)e*384 + c*3;
  float e0f = b2f(eap[0]), e1f = b2f(eap[1]), e2f = b2f(eap[2]);
  float i1 = b2f(Pi[(size_t)src*128 + c]);
  size_t ab = ((size_t)src*3)*128 + c;
  float a0 = b2f(Pa[ab]), a1 = b2f(Pa[ab+128]), a2 = b2f(Pa[ab+256]);
  size_t sb = ((size_t)src*6)*128 + c;
  float s0 = b2f(Ps[sb]),     s1 = b2f(Ps[sb+128]), s2 = b2f(Ps[sb+256]);
  float s3 = b2f(Ps[sb+384]), s4 = b2f(Ps[sb+512]), s5 = b2f(Ps[sb+640]);
  float bb = e0f*ldx(b1,c,isb) + e1f*ldx(b1,128+c,isb) + e2f*ldx(b1,256+c,isb);
  float m[9];
  m[0] =  e0f*i1 + e2f*s0 + bb;
  m[1] =  e1f*a0 + e2f*s1 + bb;
  m[2] =  e1f*a1 + e2f*s2 + bb;
  m[3] = -e1f*a0 + e2f*s1 + bb;
  m[4] =  e0f*i1 + e2f*s3 + bb;
  m[5] =  e1f*a2 + e2f*s4 + bb;
  m[6] = -e1f*a1 + e2f*s2 + bb;
  m[7] = -e1f*a2 + e2f*s4 + bb;
  m[8] =  e0f*i1 + e2f*s5 + bb;
  float* mp = msg + ((size_t)dst*128 + c)*9;
#pragma unroll
  for (int i=0;i<9;i++) atomicAdd(mp+i, m[i]);
}

// Update: F = msg*Y + Y*msg, renormalize, decompose -> D2 (bf16)
__global__ __launch_bounds__(256) void k_update(
    const float* __restrict__ msg, const u16* __restrict__ Pi,
    const u16* __restrict__ Pa, const u16* __restrict__ Ps,
    const void* __restrict__ b1,
    u16* __restrict__ D2i, u16* __restrict__ D2a, u16* __restrict__ D2s,
    int NH, const int* __restrict__ dflag)
{
  int tid = blockIdx.x*256 + threadIdx.x;
  if (tid >= NH) return;
  int isb = *dflag;
  int n = tid >> 7, c = tid & 127;
  float Mx[9];
  const float* mp = msg + (size_t)tid*9;
#pragma unroll
  for (int i=0;i<9;i++) Mx[i] = mp[i];
  float i1 = b2f(Pi[tid]);
  size_t ab = ((size_t)n*3)*128 + c;
  float a0 = b2f(Pa[ab]), a1 = b2f(Pa[ab+128]), a2 = b2f(Pa[ab+256]);
  size_t sb = ((size_t)n*6)*128 + c;
  float s0 = b2f(Ps[sb]),     s1 = b2f(Ps[sb+128]), s2 = b2f(Ps[sb+256]);
  float s3 = b2f(Ps[sb+384]), s4 = b2f(Ps[sb+512]), s5 = b2f(Ps[sb+640]);
  float B = ldx(b1,c,isb) + ldx(b1,128+c,isb) + ldx(b1,256+c,isb);
  float Y[9];
  Y[0]= i1+s0+B; Y[1]= a0+s1+B; Y[2]= a1+s2+B;
  Y[3]=-a0+s1+B; Y[4]= i1+s3+B; Y[5]= a2+s4+B;
  Y[6]=-a1+s2+B; Y[7]=-a2+s4+B; Y[8]= i1+s5+B;
  float F[9];
#pragma unroll
  for (int i=0;i<3;i++)
#pragma unroll
    for (int j=0;j<3;j++){
      float acc = 0.f;
#pragma unroll
      for (int t=0;t<3;t++)
        acc += Mx[i*3+t]*Y[t*3+j] + Y[i*3+t]*Mx[t*3+j];
      F[i*3+j] = acc;
    }
  float nrm = 0.f;
#pragma unroll
  for (int i=0;i<9;i++) nrm += F[i]*F[i];
  float inv = 1.0f/(nrm+1.0f);
  float i2 = (F[0]+F[4]+F[8])*(1.0f/3.0f);
  D2i[tid] = f2b(i2*inv);
  D2a[ab      ] = f2b(0.5f*(F[1]-F[3])*inv);
  D2a[ab + 128] = f2b(0.5f*(F[2]-F[6])*inv);
  D2a[ab + 256] = f2b(0.5f*(F[5]-F[7])*inv);
  D2s[sb      ] = f2b((F[0]-i2)*inv);
  D2s[sb + 128] = f2b(0.5f*(F[1]+F[3])*inv);
  D2s[sb + 256] = f2b(0.5f*(F[2]+F[6])*inv);
  D2s[sb + 384] = f2b((F[4]-i2)*inv);
  D2s[sb + 512] = f2b(0.5f*(F[5]+F[7])*inv);
  D2s[sb + 640] = f2b((F[8]-i2)*inv);
}

// Final: dX from P2 + b3; out = Xn + dX + dX*dX (dual-dtype out)
__global__ __launch_bounds__(256) void k_final(
    const void* __restrict__ X, const u16* __restrict__ P2i,
    const u16* __restrict__ P2a, const u16* __restrict__ P2s,
    const void* __restrict__ b3, void* __restrict__ out, int NH,
    const int* __restrict__ dflag)
{
  int tid = blockIdx.x*256 + threadIdx.x;
  if (tid >= NH) return;
  int isb = *dflag;
  int n = tid >> 7, c = tid & 127;
  float i1 = b2f(P2i[tid]);
  size_t ab = ((size_t)n*3)*128 + c;
  float a0 = b2f(P2a[ab]), a1 = b2f(P2a[ab+128]), a2 = b2f(P2a[ab+256]);
  size_t sb = ((size_t)n*6)*128 + c;
  float s0 = b2f(P2s[sb]),     s1 = b2f(P2s[sb+128]), s2 = b2f(P2s[sb+256]);
  float s3 = b2f(P2s[sb+384]), s4 = b2f(P2s[sb+512]), s5 = b2f(P2s[sb+640]);
  float B = ldx(b3,c,isb) + ldx(b3,128+c,isb) + ldx(b3,256+c,isb);
  float dX[9];
  dX[0]= i1+s0+B; dX[1]= a0+s1+B; dX[2]= a1+s2+B;
  dX[3]=-a0+s1+B; dX[4]= i1+s3+B; dX[5]= a2+s4+B;
  dX[6]=-a1+s2+B; dX[7]=-a2+s4+B; dX[8]= i1+s5+B;

  float x[9]; float nrm = 0.f;
#pragma unroll
  for (int i=0;i<9;i++){ x[i]=ldx(X,(size_t)tid*9+i,isb); nrm += x[i]*x[i]; }
  float inv = 1.0f/(nrm+1.0f);

#pragma unroll
  for (int i=0;i<3;i++)
#pragma unroll
    for (int j=0;j<3;j++){
      float acc = 0.f;
#pragma unroll
      for (int t=0;t<3;t++) acc += dX[i*3+t]*dX[t*3+j];
      float v = x[i*3+j]*inv + dX[i*3+j] + acc;
      size_t oi = (size_t)tid*9 + i*3 + j;
      if (isb) ((u16*)out)[oi] = f2b(v);
      else     ((float*)out)[oi] = v;
    }
}

extern "C" void kernel_launch(void* const* d_in, const int* in_sizes, int n_in,
                              void* d_out, int out_size, void* d_ws, size_t ws_size,
                              hipStream_t stream)
{
  const void* X    = d_in[0];
  const int*  ei   = (const int*)d_in[1];
  const void* ew   = d_in[2];
  const void* eatt = d_in[3];
  const void* W1   = d_in[4];
  const void* b1   = d_in[5];
  const void* W2a  = d_in[6];
  const void* b2a  = d_in[7];
  const void* W2b  = d_in[8];
  const void* b2b  = d_in[9];
  const void* W2c  = d_in[10];
  const void* b2c  = d_in[11];
  const void* W3   = d_in[12];
  const void* b3   = d_in[13];

  const int NH = in_sizes[0]/9;   // 20001*128
  const int E  = in_sizes[2];     // 200000
  const int N  = NH/128;

  auto aln = [](size_t x){ return (x + 255) & ~(size_t)255; };
  char* ws = (char*)d_ws;
  size_t off = 0;
  size_t o_flag = off; off += 256;
  size_t o_msg = off; off += aln((size_t)NH*9*4);
  size_t o_Di  = off; off += aln((size_t)NH*2);
  size_t o_Da  = off; off += aln((size_t)NH*6);
  size_t o_Ds  = off; off += aln((size_t)NH*12);
  size_t o_Pi  = off; off += aln((size_t)NH*2);
  size_t o_Pa  = off; off += aln((size_t)NH*6);
  size_t o_Ps  = off; off += aln((size_t)NH*12);
  size_t persistent = off;

  int EC;
  {
    size_t avail = (ws_size > persistent + 4096) ? (ws_size - persistent - 4096) : 0;
    size_t ecmax = avail / 1540;
    if (ecmax > (size_t)E) ecmax = (size_t)E;
    EC = (int)(ecmax & ~(size_t)1023);
    if (EC < 1024) EC = 1024;
  }
  size_t o_h1 = persistent;
  size_t o_h2 = o_h1 + aln((size_t)EC*256);
  size_t o_ea = o_h2 + aln((size_t)EC*512);
  size_t o_Cc = o_ea + aln((size_t)EC*768);
  (void)n_in; (void)out_size;

  int* dflag = (int*)(ws + o_flag);
  u16* Di = (u16*)(ws + o_Di);
  u16* Da = (u16*)(ws + o_Da);
  u16* Ds = (u16*)(ws + o_Ds);
  u16* Pi = (u16*)(ws + o_Pi);
  u16* Pa = (u16*)(ws + o_Pa);
  u16* Ps = (u16*)(ws + o_Ps);
  float* msg = (float*)(ws + o_msg);
  u16* h1 = (u16*)(ws + o_h1);
  u16* h2 = (u16*)(ws + o_h2);
  u16* ea = (u16*)(ws + o_ea);
  float* Cc = (float*)(ws + o_Cc);

  dim3 blk(256);
  auto gemm = [&](const void* A, size_t aoff, const void* Bw, size_t boff,
                  const void* bias, const float* rs,
                  u16* C, int M, int Ncol, int K, int flags, int aext, int bext){
    dim3 grid(Ncol/64, (M+63)/64);
    k_gemm<<<grid, blk, 0, stream>>>(A, aoff, Bw, boff, bias, rs, C, M, Ncol, K,
                                     flags, aext, bext, dflag);
  };

  // 0. sniff dtype
  k_sniff<<<1, blk, 0, stream>>>(X, dflag);
  // 1. decompose
  k_decompose<<<(NH+255)/256, blk, 0, stream>>>(X, Di, Da, Ds, NH, dflag);
  // 2. node linears (W1) -> P components
  gemm(Di, 0, W1, 0,     nullptr, nullptr, Pi, N,   128, 128, 0, 0, 1);
  gemm(Da, 0, W1, 16384, nullptr, nullptr, Pa, 3*N, 128, 128, 0, 0, 1);
  gemm(Ds, 0, W1, 32768, nullptr, nullptr, Ps, 6*N, 128, 128, 0, 0, 1);
  // 3. zero message accumulator
  {
    int n = NH*9;
    k_zero<<<(n+255)/256, blk, 0, stream>>>(msg, n);
  }
  // 4. edge MLP + message passing, chunked over edges
  for (int eoff = 0; eoff < E; eoff += EC){
    int ec = E - eoff; if (ec > EC) ec = EC;
    k_cutoff<<<(ec+255)/256, blk, 0, stream>>>(ew, eoff, Cc, ec, dflag);
    gemm(eatt, (size_t)eoff*64, W2a, 0, b2a, nullptr, h1, ec, 128, 64,  1, 1, 1);
    gemm(h1, 0,   W2b, 0, b2b, nullptr, h2, ec, 256, 128, 1, 0, 1);
    gemm(h2, 0,   W2c, 0, b2c, Cc,      ea, ec, 384, 256, 3, 0, 1);
    int total = ec*128;
    k_message<<<(total+255)/256, blk, 0, stream>>>(ei, eoff, E, ea, Pi, Pa, Ps, b1, msg, ec, dflag);
  }
  // 5. update
  k_update<<<(NH+255)/256, blk, 0, stream>>>(msg, Pi, Pa, Ps, b1, Di, Da, Ds, NH, dflag);
  // 6. node linears (W3) -> P2
  gemm(Di, 0, W3, 0,     nullptr, nullptr, Pi, N,   128, 128, 0, 0, 1);
  gemm(Da, 0, W3, 16384, nullptr, nullptr, Pa, 3*N, 128, 128, 0, 0, 1);
  gemm(Ds, 0, W3, 32768, nullptr, nullptr, Ps, 6*N, 128, 128, 0, 0, 1);
  // 7. final output
  k_final<<<(NH+255)/256, blk, 0, stream>>>(X, Pi, Pa, Ps, b3, d_out, NH, dflag);
}

// Round 4
// 1003.735 us; speedup vs baseline: 8.5126x; 8.5126x over previous
//
#include <hip/hip_runtime.h>
#include <math.h>
#include <stdint.h>

typedef unsigned short u16;
typedef __attribute__((ext_vector_type(8))) short short8;   // 8 bf16 (4 VGPRs)
typedef __attribute__((ext_vector_type(4))) float floatx4;  // MFMA acc

__device__ __forceinline__ float b2f(u16 u){
  union{unsigned int i; float f;} v; v.i = ((unsigned int)u)<<16; return v.f;
}
__device__ __forceinline__ u16 f2b(float f){
  union{unsigned int i; float f;} v; v.f = f;
  unsigned int r = (v.i + 0x7FFFu + ((v.i>>16)&1u))>>16;
  return (u16)r;
}
// dual-dtype external loads: isb=1 -> bf16(u16), isb=0 -> float32
__device__ __forceinline__ float ldx(const void* p, size_t i, int isb){
  return isb ? b2f(((const u16*)p)[i]) : ((const float*)p)[i];
}
// load 16 contiguous elements as bf16 bits into o[16]
__device__ __forceinline__ void ldg16_bf(const u16* p, u16* o){
  uint4 v0 = *reinterpret_cast<const uint4*>(p);
  uint4 v1 = *reinterpret_cast<const uint4*>(p+8);
  unsigned int u[8] = {v0.x,v0.y,v0.z,v0.w,v1.x,v1.y,v1.z,v1.w};
#pragma unroll
  for (int i=0;i<8;i++){ o[2*i] = (u16)(u[i]&0xffffu); o[2*i+1] = (u16)(u[i]>>16); }
}
__device__ __forceinline__ void ldg16_f32(const float* p, u16* o){
#pragma unroll
  for (int i=0;i<4;i++){
    float4 v = reinterpret_cast<const float4*>(p)[i];
    o[4*i+0]=f2b(v.x); o[4*i+1]=f2b(v.y); o[4*i+2]=f2b(v.z); o[4*i+3]=f2b(v.w);
  }
}
__device__ __forceinline__ uint4 pack8(const u16* o){
  uint4 r;
  r.x = (unsigned int)o[0] | ((unsigned int)o[1]<<16);
  r.y = (unsigned int)o[2] | ((unsigned int)o[3]<<16);
  r.z = (unsigned int)o[4] | ((unsigned int)o[5]<<16);
  r.w = (unsigned int)o[6] | ((unsigned int)o[7]<<16);
  return r;
}

// dtype sniffer: bf16 N(0,1) data has exponent field in [110,139] for ~all
// even-indexed u16s; f32 low-mantissa halves are uniform (~12% in window).
__global__ void k_sniff(const void* __restrict__ X, int* __restrict__ flag)
{
  __shared__ int cnt;
  if (threadIdx.x==0) cnt = 0;
  __syncthreads();
  int c = 0;
  for (int t = threadIdx.x; t < 512; t += 256){
    unsigned int u = ((const u16*)X)[2*t];
    int e = (u >> 7) & 0xFF;
    if (e >= 110 && e <= 139) c++;
  }
  atomicAdd(&cnt, c);
  __syncthreads();
  if (threadIdx.x==0) *flag = (cnt > 300) ? 1 : 0;
}

__global__ __launch_bounds__(256) void k_zero(float* __restrict__ p, int n)
{
  int i = blockIdx.x*256 + threadIdx.x;
  if (i < n) p[i] = 0.f;
}
__global__ __launch_bounds__(256) void k_zero_int(int* __restrict__ p, int n)
{
  int i = blockIdx.x*256 + threadIdx.x;
  if (i < n) p[i] = 0;
}

// CSR build: histogram of dst, block-scan to rowptr (+fill copy), scatter.
__global__ __launch_bounds__(256) void k_hist(
    const int* __restrict__ ei, int* __restrict__ counts, int E)
{
  int e = blockIdx.x*256 + threadIdx.x;
  if (e < E) atomicAdd(&counts[ei[e]], 1);
}
__global__ __launch_bounds__(256) void k_scan(
    const int* __restrict__ counts, int* __restrict__ rowptr,
    int* __restrict__ fill, int N)
{
  __shared__ int sm[256];
  __shared__ int carry;
  int tid = threadIdx.x;
  if (tid == 0) carry = 0;
  __syncthreads();
  for (int base = 0; base < N; base += 256){
    int v = (base+tid < N) ? counts[base+tid] : 0;
    sm[tid] = v;
    __syncthreads();
    for (int off=1; off<256; off<<=1){
      int t = (tid >= off) ? sm[tid-off] : 0;
      __syncthreads();
      sm[tid] += t;
      __syncthreads();
    }
    int excl = carry + sm[tid] - v;
    if (base+tid < N){ rowptr[base+tid] = excl; fill[base+tid] = excl; }
    __syncthreads();
    if (tid == 0) carry += sm[255];
    __syncthreads();
  }
  if (tid == 0) rowptr[N] = carry;
}
__global__ __launch_bounds__(256) void k_scatter(
    const int* __restrict__ ei, int* __restrict__ fill,
    int* __restrict__ eorder, int E)
{
  int e = blockIdx.x*256 + threadIdx.x;
  if (e >= E) return;
  int d = ei[e];
  int pos = atomicAdd(&fill[d], 1);
  eorder[pos] = e;
}

// normalize X, decompose into 10 independent components (bf16)
__global__ __launch_bounds__(256) void k_decompose(
    const void* __restrict__ X, u16* __restrict__ Di, u16* __restrict__ Da,
    u16* __restrict__ Ds, int NH, const int* __restrict__ dflag)
{
  int tid = blockIdx.x*256 + threadIdx.x;
  if (tid >= NH) return;
  int isb = *dflag;
  int n = tid >> 7, k = tid & 127;
  float x[9]; float nrm = 0.f;
#pragma unroll
  for (int i=0;i<9;i++){ x[i]=ldx(X,(size_t)tid*9+i,isb); nrm += x[i]*x[i]; }
  float inv = 1.0f/(nrm+1.0f);
#pragma unroll
  for (int i=0;i<9;i++) x[i]*=inv;
  float i0 = (x[0]+x[4]+x[8])*(1.0f/3.0f);
  Di[tid] = f2b(i0);
  size_t ab = ((size_t)n*3)*128 + k;
  Da[ab      ] = f2b(0.5f*(x[1]-x[3]));
  Da[ab + 128] = f2b(0.5f*(x[2]-x[6]));
  Da[ab + 256] = f2b(0.5f*(x[5]-x[7]));
  size_t sb = ((size_t)n*6)*128 + k;
  Ds[sb      ] = f2b(x[0]-i0);
  Ds[sb + 128] = f2b(0.5f*(x[1]+x[3]));
  Ds[sb + 256] = f2b(0.5f*(x[2]+x[6]));
  Ds[sb + 384] = f2b(x[4]-i0);
  Ds[sb + 512] = f2b(0.5f*(x[5]+x[7]));
  Ds[sb + 640] = f2b(x[8]-i0);
}

// ---------------------------------------------------------------------------
// MFMA GEMM: C[M,Ncol](bf16) = A[M,K] * B[Ncol,K]^T  (+bias, silu, rowscale)
// 128x128 tile, 4 waves (2x2 of 64x64), BK=32, mfma_f32_16x16x32_bf16.
// A row gather via rowidx (for edge-sorted eatt). flags: 1=silu, 2=rowscale,
// 4=permute B rows/bias cols with (i&127)*3+(i>>7) (Ncol==384 reshape trick).
// Requires: Ncol %128==0, K %32==0.
// ---------------------------------------------------------------------------
__global__ __launch_bounds__(256) void k_mfma_gemm(
    const void* __restrict__ A, size_t aoff, const int* __restrict__ rowidx, int ridx0,
    const void* __restrict__ Bw, size_t boff,
    const void* __restrict__ bias, const float* __restrict__ rowscale,
    u16* __restrict__ C, int M, int Ncol, int K, int flags,
    int aext, int bext, const int* __restrict__ dflag)
{
  __shared__ u16 AsU[128][40];   // 32 cols + 8 pad (bank spread), 16B-aligned rows
  __shared__ u16 BsU[128][40];
  int isb = *dflag;
  int isbA = aext ? isb : 1;
  int isbB = bext ? isb : 1;
  int tid = threadIdx.x;
  int lane = tid & 63, l15 = lane & 15, q = lane >> 4;
  int wid = tid >> 6, wm = wid & 1, wn = wid >> 1;
  int n0 = blockIdx.x * 128, m0 = blockIdx.y * 128;
  int r = tid >> 1, cs = (tid & 1) * 16;

  floatx4 acc[4][4];
#pragma unroll
  for (int i=0;i<4;i++)
#pragma unroll
    for (int j=0;j<4;j++) acc[i][j] = (floatx4)0.f;

  long arow = -1;
  {
    int gm = m0 + r;
    if (gm < M) arow = rowidx ? (long)rowidx[ridx0 + gm] : (long)gm;
  }
  int brow_g = n0 + r;
  int bsrc = (flags & 4) ? ((brow_g & 127)*3 + (brow_g >> 7)) : brow_g;

  for (int k0 = 0; k0 < K; k0 += 32){
    u16 ta[16], tb[16];
    if (arow >= 0){
      size_t base = aoff + (size_t)arow*K + k0 + cs;
      if (isbA) ldg16_bf((const u16*)A + base, ta);
      else      ldg16_f32((const float*)A + base, ta);
    } else {
#pragma unroll
      for (int i=0;i<16;i++) ta[i]=0;
    }
    {
      size_t base = boff + (size_t)bsrc*K + k0 + cs;
      if (isbB) ldg16_bf((const u16*)Bw + base, tb);
      else      ldg16_f32((const float*)Bw + base, tb);
    }
    __syncthreads();
    *reinterpret_cast<uint4*>(&AsU[r][cs])   = pack8(ta);
    *reinterpret_cast<uint4*>(&AsU[r][cs+8]) = pack8(ta+8);
    *reinterpret_cast<uint4*>(&BsU[r][cs])   = pack8(tb);
    *reinterpret_cast<uint4*>(&BsU[r][cs+8]) = pack8(tb+8);
    __syncthreads();
    short8 av[4], bv[4];
#pragma unroll
    for (int mt=0; mt<4; mt++)
      av[mt] = *reinterpret_cast<const short8*>(&AsU[wm*64 + mt*16 + l15][q*8]);
#pragma unroll
    for (int nt=0; nt<4; nt++)
      bv[nt] = *reinterpret_cast<const short8*>(&BsU[wn*64 + nt*16 + l15][q*8]);
#pragma unroll
    for (int mt=0; mt<4; mt++)
#pragma unroll
      for (int nt=0; nt<4; nt++)
        acc[mt][nt] = __builtin_amdgcn_mfma_f32_16x16x32_bf16(av[mt], bv[nt], acc[mt][nt], 0, 0, 0);
  }

  float biasv[4];
#pragma unroll
  for (int nt=0; nt<4; nt++){
    int col = n0 + wn*64 + nt*16 + l15;
    int bcol = (flags & 4) ? ((col & 127)*3 + (col >> 7)) : col;
    biasv[nt] = bias ? ldx(bias, bcol, isbB) : 0.f;
  }
#pragma unroll
  for (int mt=0; mt<4; mt++){
#pragma unroll
    for (int reg=0; reg<4; reg++){
      int row = m0 + wm*64 + mt*16 + q*4 + reg;
      if (row >= M) continue;
      float rs = (flags & 2) ? rowscale[row] : 1.0f;
#pragma unroll
      for (int nt=0; nt<4; nt++){
        int col = n0 + wn*64 + nt*16 + l15;
        float t = acc[mt][nt][reg] + biasv[nt];
        if (flags & 1) t = t / (1.0f + expf(-t));
        C[(size_t)row*Ncol + col] = f2b(t*rs);
      }
    }
  }
}

// cutoff factor per sorted edge (row i of chunk = edge eorder[c0+i])
__global__ __launch_bounds__(256) void k_cutoff(
    const void* __restrict__ ew, const int* __restrict__ eorder, int c0,
    float* __restrict__ Cc, int ec, const int* __restrict__ dflag)
{
  int i = blockIdx.x*256 + threadIdx.x;
  if (i >= ec) return;
  int e = eorder[c0 + i];
  float w = ldx(ew, e, *dflag);
  float c = 0.0f;
  if (w < 4.5f) c = 0.5f*(cosf(w*0.6981317007977318f) + 1.0f);
  Cc[i] = c;
}

// ---------------------------------------------------------------------------
// Gather message passing: block per dst node, 128 threads = channels.
// Edges sorted by dst; chunk [c0,c1). ea chunk layout [ec][3][128] (permB).
// Non-atomic msg += (one block per node; chunks sequential on stream).
// msg layout [9][NH] f32 (coalesced).
// ---------------------------------------------------------------------------
__global__ __launch_bounds__(128) void k_gather(
    const int* __restrict__ rowptr, const int* __restrict__ eorder,
    const int* __restrict__ ei, int E, int c0, int c1,
    const u16* __restrict__ ea,
    const u16* __restrict__ Pi, const u16* __restrict__ Pa,
    const u16* __restrict__ Ps, const void* __restrict__ b1,
    float* __restrict__ msg, int NH, const int* __restrict__ dflag)
{
  int n = blockIdx.x;
  int lo = rowptr[n], hi = rowptr[n+1];
  if (lo < c0) lo = c0;
  if (hi > c1) hi = c1;
  if (lo >= hi) return;
  int isb = *dflag;
  int c = threadIdx.x;
  float b0 = ldx(b1,c,isb), b1f = ldx(b1,128+c,isb), b2v = ldx(b1,256+c,isb);
  float m[9];
#pragma unroll
  for (int i=0;i<9;i++) m[i]=0.f;
  for (int idx = lo; idx < hi; idx++){
    int e = eorder[idx];
    int src = ei[E + e];
    const u16* er = ea + (size_t)(idx - c0)*384;
    float e0f = b2f(er[c]), e1f = b2f(er[128+c]), e2f = b2f(er[256+c]);
    float i1 = b2f(Pi[(size_t)src*128 + c]);
    size_t ab = (size_t)src*384 + c;
    float a0 = b2f(Pa[ab]), a1 = b2f(Pa[ab+128]), a2 = b2f(Pa[ab+256]);
    size_t sb = (size_t)src*768 + c;
    float s0 = b2f(Ps[sb]),     s1 = b2f(Ps[sb+128]), s2 = b2f(Ps[sb+256]);
    float s3 = b2f(Ps[sb+384]), s4 = b2f(Ps[sb+512]), s5 = b2f(Ps[sb+640]);
    float bb = e0f*b0 + e1f*b1f + e2f*b2v;
    float t0 = e0f*i1;
    m[0] += t0 + e2f*s0 + bb;
    m[1] += e1f*a0 + e2f*s1 + bb;
    m[2] += e1f*a1 + e2f*s2 + bb;
    m[3] += -e1f*a0 + e2f*s1 + bb;
    m[4] += t0 + e2f*s3 + bb;
    m[5] += e1f*a2 + e2f*s4 + bb;
    m[6] += -e1f*a1 + e2f*s2 + bb;
    m[7] += -e1f*a2 + e2f*s4 + bb;
    m[8] += t0 + e2f*s5 + bb;
  }
  size_t o = (size_t)n*128 + c;
#pragma unroll
  for (int i=0;i<9;i++) msg[(size_t)i*NH + o] += m[i];
}

// Update: F = msg*Y + Y*msg, renormalize, decompose -> D2 (bf16)
__global__ __launch_bounds__(256) void k_update(
    const float* __restrict__ msg, const u16* __restrict__ Pi,
    const u16* __restrict__ Pa, const u16* __restrict__ Ps,
    const void* __restrict__ b1,
    u16* __restrict__ D2i, u16* __restrict__ D2a, u16* __restrict__ D2s,
    int NH, const int* __restrict__ dflag)
{
  int tid = blockIdx.x*256 + threadIdx.x;
  if (tid >= NH) return;
  int isb = *dflag;
  int n = tid >> 7, c = tid & 127;
  float Mx[9];
#pragma unroll
  for (int i=0;i<9;i++) Mx[i] = msg[(size_t)i*NH + tid];
  float i1 = b2f(Pi[tid]);
  size_t ab = ((size_t)n*3)*128 + c;
  float a0 = b2f(Pa[ab]), a1 = b2f(Pa[ab+128]), a2 = b2f(Pa[ab+256]);
  size_t sb = ((size_t)n*6)*128 + c;
  float s0 = b2f(Ps[sb]),     s1 = b2f(Ps[sb+128]), s2 = b2f(Ps[sb+256]);
  float s3 = b2f(Ps[sb+384]), s4 = b2f(Ps[sb+512]), s5 = b2f(Ps[sb+640]);
  float B = ldx(b1,c,isb) + ldx(b1,128+c,isb) + ldx(b1,256+c,isb);
  float Y[9];
  Y[0]= i1+s0+B; Y[1]= a0+s1+B; Y[2]= a1+s2+B;
  Y[3]=-a0+s1+B; Y[4]= i1+s3+B; Y[5]= a2+s4+B;
  Y[6]=-a1+s2+B; Y[7]=-a2+s4+B; Y[8]= i1+s5+B;
  float F[9];
#pragma unroll
  for (int i=0;i<3;i++)
#pragma unroll
    for (int j=0;j<3;j++){
      float acc = 0.f;
#pragma unroll
      for (int t=0;t<3;t++)
        acc += Mx[i*3+t]*Y[t*3+j] + Y[i*3+t]*Mx[t*3+j];
      F[i*3+j] = acc;
    }
  float nrm = 0.f;
#pragma unroll
  for (int i=0;i<9;i++) nrm += F[i]*F[i];
  float inv = 1.0f/(nrm+1.0f);
  float i2 = (F[0]+F[4]+F[8])*(1.0f/3.0f);
  D2i[tid] = f2b(i2*inv);
  D2a[ab      ] = f2b(0.5f*(F[1]-F[3])*inv);
  D2a[ab + 128] = f2b(0.5f*(F[2]-F[6])*inv);
  D2a[ab + 256] = f2b(0.5f*(F[5]-F[7])*inv);
  D2s[sb      ] = f2b((F[0]-i2)*inv);
  D2s[sb + 128] = f2b(0.5f*(F[1]+F[3])*inv);
  D2s[sb + 256] = f2b(0.5f*(F[2]+F[6])*inv);
  D2s[sb + 384] = f2b((F[4]-i2)*inv);
  D2s[sb + 512] = f2b(0.5f*(F[5]+F[7])*inv);
  D2s[sb + 640] = f2b((F[8]-i2)*inv);
}

// Final: dX from P2 + b3; out = Xn + dX + dX*dX (dual-dtype out)
__global__ __launch_bounds__(256) void k_final(
    const void* __restrict__ X, const u16* __restrict__ P2i,
    const u16* __restrict__ P2a, const u16* __restrict__ P2s,
    const void* __restrict__ b3, void* __restrict__ out, int NH,
    const int* __restrict__ dflag)
{
  int tid = blockIdx.x*256 + threadIdx.x;
  if (tid >= NH) return;
  int isb = *dflag;
  int n = tid >> 7, c = tid & 127;
  float i1 = b2f(P2i[tid]);
  size_t ab = ((size_t)n*3)*128 + c;
  float a0 = b2f(P2a[ab]), a1 = b2f(P2a[ab+128]), a2 = b2f(P2a[ab+256]);
  size_t sb = ((size_t)n*6)*128 + c;
  float s0 = b2f(P2s[sb]),     s1 = b2f(P2s[sb+128]), s2 = b2f(P2s[sb+256]);
  float s3 = b2f(P2s[sb+384]), s4 = b2f(P2s[sb+512]), s5 = b2f(P2s[sb+640]);
  float B = ldx(b3,c,isb) + ldx(b3,128+c,isb) + ldx(b3,256+c,isb);
  float dX[9];
  dX[0]= i1+s0+B; dX[1]= a0+s1+B; dX[2]= a1+s2+B;
  dX[3]=-a0+s1+B; dX[4]= i1+s3+B; dX[5]= a2+s4+B;
  dX[6]=-a1+s2+B; dX[7]=-a2+s4+B; dX[8]= i1+s5+B;

  float x[9]; float nrm = 0.f;
#pragma unroll
  for (int i=0;i<9;i++){ x[i]=ldx(X,(size_t)tid*9+i,isb); nrm += x[i]*x[i]; }
  float inv = 1.0f/(nrm+1.0f);

#pragma unroll
  for (int i=0;i<3;i++)
#pragma unroll
    for (int j=0;j<3;j++){
      float acc = 0.f;
#pragma unroll
      for (int t=0;t<3;t++) acc += dX[i*3+t]*dX[t*3+j];
      float v = x[i*3+j]*inv + dX[i*3+j] + acc;
      size_t oi = (size_t)tid*9 + i*3 + j;
      if (isb) ((u16*)out)[oi] = f2b(v);
      else     ((float*)out)[oi] = v;
    }
}

extern "C" void kernel_launch(void* const* d_in, const int* in_sizes, int n_in,
                              void* d_out, int out_size, void* d_ws, size_t ws_size,
                              hipStream_t stream)
{
  const void* X    = d_in[0];
  const int*  ei   = (const int*)d_in[1];
  const void* ew   = d_in[2];
  const void* eatt = d_in[3];
  const void* W1   = d_in[4];
  const void* b1   = d_in[5];
  const void* W2a  = d_in[6];
  const void* b2a  = d_in[7];
  const void* W2b  = d_in[8];
  const void* b2b  = d_in[9];
  const void* W2c  = d_in[10];
  const void* b2c  = d_in[11];
  const void* W3   = d_in[12];
  const void* b3   = d_in[13];

  const int NH = in_sizes[0]/9;   // 20001*128
  const int E  = in_sizes[2];     // 200000
  const int N  = NH/128;

  auto aln = [](size_t x){ return (x + 255) & ~(size_t)255; };
  char* ws = (char*)d_ws;
  size_t off = 0;
  size_t o_flag = off; off += 256;
  size_t o_msg  = off; off += aln((size_t)NH*9*4);
  size_t o_Di   = off; off += aln((size_t)NH*2);
  size_t o_Da   = off; off += aln((size_t)NH*6);
  size_t o_Ds   = off; off += aln((size_t)NH*12);
  size_t o_Pi   = off; off += aln((size_t)NH*2);
  size_t o_Pa   = off; off += aln((size_t)NH*6);
  size_t o_Ps   = off; off += aln((size_t)NH*12);
  size_t o_cnt  = off; off += aln((size_t)N*4);
  size_t o_rp   = off; off += aln((size_t)(N+1)*4);
  size_t o_fill = off; off += aln((size_t)N*4);
  size_t o_eord = off; off += aln((size_t)E*4);
  size_t persistent = off;

  // Per-edge chunk footprint: h1(256B)+h2(512B)+ea(768B)+Cc(4B) = 1540B
  int EC;
  {
    size_t avail = (ws_size > persistent + 4096) ? (ws_size - persistent - 4096) : 0;
    size_t ecmax = avail / 1540;
    if (ecmax > (size_t)E) ecmax = (size_t)E;
    EC = (int)(ecmax & ~(size_t)1023);
    if (EC < 1024) EC = 1024;
  }
  size_t o_h1 = persistent;
  size_t o_h2 = o_h1 + aln((size_t)EC*256);
  size_t o_ea = o_h2 + aln((size_t)EC*512);
  size_t o_Cc = o_ea + aln((size_t)EC*768);
  (void)n_in; (void)out_size;

  int* dflag = (int*)(ws + o_flag);
  u16* Di = (u16*)(ws + o_Di);
  u16* Da = (u16*)(ws + o_Da);
  u16* Ds = (u16*)(ws + o_Ds);
  u16* Pi = (u16*)(ws + o_Pi);
  u16* Pa = (u16*)(ws + o_Pa);
  u16* Ps = (u16*)(ws + o_Ps);
  float* msg = (float*)(ws + o_msg);
  int* counts = (int*)(ws + o_cnt);
  int* rowptr = (int*)(ws + o_rp);
  int* fill   = (int*)(ws + o_fill);
  int* eorder = (int*)(ws + o_eord);
  u16* h1 = (u16*)(ws + o_h1);
  u16* h2 = (u16*)(ws + o_h2);
  u16* ea = (u16*)(ws + o_ea);
  float* Cc = (float*)(ws + o_Cc);

  dim3 blk(256);
  auto gemm = [&](const void* A, size_t aoff, const int* ridx, int ridx0,
                  const void* Bw, size_t boff, const void* bias, const float* rs,
                  u16* C, int M, int Ncol, int K, int flags, int aext, int bext){
    dim3 grid(Ncol/128, (M+127)/128);
    k_mfma_gemm<<<grid, blk, 0, stream>>>(A, aoff, ridx, ridx0, Bw, boff, bias, rs,
                                          C, M, Ncol, K, flags, aext, bext, dflag);
  };

  // 0. sniff dtype
  k_sniff<<<1, blk, 0, stream>>>(X, dflag);
  // 1. decompose
  k_decompose<<<(NH+255)/256, blk, 0, stream>>>(X, Di, Da, Ds, NH, dflag);
  // 2. node linears (W1) -> P components
  gemm(Di, 0, nullptr, 0, W1, 0,     nullptr, nullptr, Pi, N,   128, 128, 0, 0, 1);
  gemm(Da, 0, nullptr, 0, W1, 16384, nullptr, nullptr, Pa, 3*N, 128, 128, 0, 0, 1);
  gemm(Ds, 0, nullptr, 0, W1, 32768, nullptr, nullptr, Ps, 6*N, 128, 128, 0, 0, 1);
  // 3. zero msg accumulator; build CSR (sort edges by dst)
  k_zero<<<((NH*9)+255)/256, blk, 0, stream>>>(msg, NH*9);
  k_zero_int<<<(N+255)/256, blk, 0, stream>>>(counts, N);
  k_hist<<<(E+255)/256, blk, 0, stream>>>(ei, counts, E);
  k_scan<<<1, blk, 0, stream>>>(counts, rowptr, fill, N);
  k_scatter<<<(E+255)/256, blk, 0, stream>>>(ei, fill, eorder, E);
  // 4. edge MLP (dst-sorted order) + gather message passing, chunked
  for (int c0 = 0; c0 < E; c0 += EC){
    int ec = E - c0; if (ec > EC) ec = EC;
    k_cutoff<<<(ec+255)/256, blk, 0, stream>>>(ew, eorder, c0, Cc, ec, dflag);
    gemm(eatt, 0, eorder, c0, W2a, 0, b2a, nullptr, h1, ec, 128, 64,  1, 1, 1);
    gemm(h1, 0, nullptr, 0,   W2b, 0, b2b, nullptr, h2, ec, 256, 128, 1, 0, 1);
    gemm(h2, 0, nullptr, 0,   W2c, 0, b2c, Cc,      ea, ec, 384, 256, 1|2|4, 0, 1);
    k_gather<<<N, dim3(128), 0, stream>>>(rowptr, eorder, ei, E, c0, c0+ec,
                                          ea, Pi, Pa, Ps, b1, msg, NH, dflag);
  }
  // 5. update (writes D2 into D buffers; D dead)
  k_update<<<(NH+255)/256, blk, 0, stream>>>(msg, Pi, Pa, Ps, b1, Di, Da, Ds, NH, dflag);
  // 6. node linears (W3) -> P2 (reuses P buffers)
  gemm(Di, 0, nullptr, 0, W3, 0,     nullptr, nullptr, Pi, N,   128, 128, 0, 0, 1);
  gemm(Da, 0, nullptr, 0, W3, 16384, nullptr, nullptr, Pa, 3*N, 128, 128, 0, 0, 1);
  gemm(Ds, 0, nullptr, 0, W3, 32768, nullptr, nullptr, Ps, 6*N, 128, 128, 0, 0, 1);
  // 7. final output
  k_final<<<(NH+255)/256, blk, 0, stream>>>(X, Pi, Pa, Ps, b3, d_out, NH, dflag);
}